// Round 3
// baseline (306.495 us; speedup 1.0000x reference)
//
#include <hip/hip_runtime.h>

#define B_ 4
#define N_ 1000000
#define K_ 2048
#define P_ 1000
#define CAP_ 8192
#define THR_ 0.7f
#define NF4_ 500000     // float4 count per batch of (N,2) float array
#define META_STRIDE 32  // u32 per batch -> 128 B: counters on separate cache lines
#define TILE_ 512       // rank tile (candidates per tile-chunk)
#define NCH_ (CAP_ / TILE_)  // 16 tile chunks max

// ---- workspace layout (bytes) ----
// hist   : B * 8192 * 4 = 131,072   (16384 buckets/batch, packed u16 pairs)
// meta   : 1024
// rowAny : B * 32 * 8 = 1,024       (2048-bit "row has suppression bits" bitmap)
// cand   : B * CAP * 8 = 262,144
// boxes  : B * K * 16 = 131,072
// mask   : B * K * 32 * 8 = 2,097,152  (pre-zeroed by hist blocks; sparse writes)
// partial: B * NCH * CAP * 4 = 2,097,152 (rank partials; no aliasing)
#define OFF_HIST 0
#define OFF_META 131072
#define OFF_ROWANY 132096
#define OFF_CAND 133120
#define OFF_BOX  395264
#define OFF_MASK 526336
#define OFF_PART 2623488

__device__ __forceinline__ unsigned fkey(float f) {
  unsigned u = __float_as_uint(f);
  return (u & 0x80000000u) ? ~u : (u | 0x80000000u);
}

// bucket in [0, 16384): scores >= 0 have key top16 in [0x8000, 0xBFFF]; clamp others
__device__ __forceinline__ int b16of(unsigned key) {
  int x = (int)(key >> 16) - 0x8000;
  x = x < 0 ? 0 : x;
  return x > 0x3FFF ? 0x3FFF : x;
}

__device__ __forceinline__ unsigned long long readlane64(unsigned long long v, int l) {
  unsigned lo = (unsigned)__builtin_amdgcn_readlane((int)(unsigned)(v & 0xffffffffull), l);
  unsigned hi = (unsigned)__builtin_amdgcn_readlane((int)(unsigned)(v >> 32), l);
  return ((unsigned long long)hi << 32) | (unsigned long long)lo;
}

#define PIN16(k) asm volatile("" : "+v"(k[0]), "+v"(k[1]), "+v"(k[2]), "+v"(k[3]), \
                                   "+v"(k[4]), "+v"(k[5]), "+v"(k[6]), "+v"(k[7]), \
                                   "+v"(k[8]), "+v"(k[9]), "+v"(k[10]), "+v"(k[11]), \
                                   "+v"(k[12]), "+v"(k[13]), "+v"(k[14]), "+v"(k[15]))

// ---- K1: LDS-privatized 16k-bucket histogram (packed u16), + zero mask buffer ----
__global__ void __launch_bounds__(512) hist_kernel(const float4* __restrict__ probs4,
                                                   unsigned* __restrict__ hist,
                                                   uint4* __restrict__ maskz) {
  int b = blockIdx.y;
  __shared__ unsigned h[8192];
  for (int i = threadIdx.x; i < 8192; i += 512) h[i] = 0u;
  // side duty: zero the mask buffer (used much later by mask/nms)
  {
    unsigned gid = (unsigned)(b * 124 + blockIdx.x);
    if (threadIdx.x < 320u) {
      unsigned zi = gid * 320u + threadIdx.x;
      if (zi < 131072u) maskz[zi] = make_uint4(0u, 0u, 0u, 0u);
    }
  }
  __syncthreads();
  const float4* p4 = probs4 + (size_t)b * NF4_;
  int base = blockIdx.x * 4096;
  float4 v[8];
#pragma unroll
  for (int c = 0; c < 8; ++c) {
    int i4 = base + c * 512 + threadIdx.x;
    v[c] = (i4 < NF4_) ? p4[i4] : make_float4(0.f, 0.f, 0.f, 0.f);
  }
  unsigned k[16];
#pragma unroll
  for (int c = 0; c < 8; ++c) {
    k[2 * c] = (unsigned)b16of(fkey(v[c].y));
    k[2 * c + 1] = (unsigned)b16of(fkey(v[c].w));
  }
  PIN16(k);
#pragma unroll
  for (int c = 0; c < 8; ++c) {
    int i4 = base + c * 512 + threadIdx.x;
    if (i4 < NF4_) {
      unsigned b0 = k[2 * c], b1 = k[2 * c + 1];
      atomicAdd(&h[b0 >> 1], 1u << ((b0 & 1u) << 4));
      atomicAdd(&h[b1 >> 1], 1u << ((b1 & 1u) << 4));
    }
  }
  __syncthreads();
  unsigned* g = hist + b * 8192;
  for (int w = threadIdx.x; w < 8192; w += 512) {
    unsigned x = h[w];
    if (x) atomicAdd(&g[w], x);  // packed add: halves < 65536, no carry-out
  }
}

// ---- K2: fused coarse+select — find smallest bucket cb with suffix count >= K ----
__global__ void select_kernel(const unsigned* __restrict__ hist, unsigned* __restrict__ meta) {
  int b = blockIdx.x, t = threadIdx.x;  // 256 threads
  const unsigned* g = hist + b * 8192;  // 16384 buckets packed u16
  __shared__ unsigned part[256];
  __shared__ unsigned gsum[64];
  __shared__ unsigned suf[256];
  __shared__ int tc_s;
  __shared__ unsigned above_s;
  // coarse: 64 groups of 256 buckets (=128 u32 words); 4 threads/group
  {
    int grp = t >> 2, q = t & 3;
    const unsigned* p = g + grp * 128 + q * 32;
    unsigned s = 0;
#pragma unroll 8
    for (int i = 0; i < 32; ++i) { unsigned x = p[i]; s += (x & 0xFFFFu) + (x >> 16); }
    part[t] = s;
  }
  __syncthreads();
  if (t < 64) gsum[t] = part[4 * t] + part[4 * t + 1] + part[4 * t + 2] + part[4 * t + 3];
  __syncthreads();
  if (t < 64) suf[t] = gsum[t];
  __syncthreads();
  for (int off = 1; off < 64; off <<= 1) {
    unsigned add = (t < 64 && t + off < 64) ? suf[t + off] : 0u;
    __syncthreads();
    if (t < 64) suf[t] += add;
    __syncthreads();
  }
  if (t < 64) {
    unsigned nxt = (t < 63) ? suf[t + 1] : 0u;
    if (suf[t] >= K_ && (t == 63 || nxt < K_)) { tc_s = t; above_s = nxt; }
  }
  __syncthreads();
  int tc = tc_s;
  unsigned above = above_s;
  // fine: buckets [tc*256, tc*256+256)
  unsigned wv = g[tc * 128 + (t >> 1)];
  unsigned bs = (t & 1) ? (wv >> 16) : (wv & 0xFFFFu);
  __syncthreads();
  suf[t] = bs;
  __syncthreads();
  for (int off = 1; off < 256; off <<= 1) {
    unsigned add = (t + off < 256) ? suf[t + off] : 0u;
    __syncthreads();
    suf[t] += add;
    __syncthreads();
  }
  unsigned nxt2 = (t < 255) ? suf[t + 1] : 0u;
  if (above + suf[t] >= K_ && (t == 255 || above + nxt2 < K_))
    meta[b * META_STRIDE + 0] = (unsigned)(tc * 256 + t);
}

// ---- K3: compact candidates (bucket >= cb), LDS-buffered, 1 global atomic/block ----
__global__ void __launch_bounds__(256) compact_kernel(const float4* __restrict__ probs4,
                                                      unsigned* __restrict__ meta,
                                                      uint2* __restrict__ cand) {
  int b = blockIdx.y;
  __shared__ unsigned lcnt, gbase_s;
  __shared__ uint2 buf[4096];
  if (threadIdx.x == 0) lcnt = 0u;
  __syncthreads();
  int cb = (int)meta[b * META_STRIDE + 0];
  const float4* p4 = probs4 + (size_t)b * NF4_;
  int base = blockIdx.x * 2048;
  int lane = threadIdx.x & 63;
  float4 v[8];
#pragma unroll
  for (int c = 0; c < 8; ++c) {
    int i4 = base + c * 256 + threadIdx.x;
    v[c] = (i4 < NF4_) ? p4[i4] : make_float4(0.f, 0.f, 0.f, 0.f);
  }
  unsigned k[16];
#pragma unroll
  for (int c = 0; c < 8; ++c) { k[2 * c] = fkey(v[c].y); k[2 * c + 1] = fkey(v[c].w); }
  PIN16(k);
#pragma unroll
  for (int c = 0; c < 8; ++c) {
#pragma unroll
    for (int s = 0; s < 2; ++s) {
      int i4 = base + c * 256 + threadIdx.x;
      unsigned key = k[2 * c + s];
      bool pass = (i4 < NF4_) && (b16of(key) >= cb);
      unsigned long long m = __ballot(pass);
      if (m) {
        int leader = __ffsll(m) - 1;
        unsigned wbase = 0;
        if (lane == leader) wbase = atomicAdd(&lcnt, (unsigned)__popcll(m));
        wbase = __shfl(wbase, leader, 64);
        if (pass) {
          unsigned pos = wbase + (unsigned)__popcll(m & ((1ull << lane) - 1ull));
          buf[pos] = make_uint2(key, (unsigned)(2 * i4 + s));
        }
      }
    }
  }
  __syncthreads();
  unsigned cnt = lcnt;
  if (threadIdx.x == 0) gbase_s = atomicAdd(&meta[b * META_STRIDE + 1], cnt);
  __syncthreads();
  unsigned gbase = gbase_s;
  for (unsigned i = threadIdx.x; i < cnt; i += 256) {
    unsigned pos = gbase + i;
    if (pos < CAP_) cand[(size_t)b * CAP_ + pos] = buf[i];
  }
}

// ---- K4: exact rank by counting, 2D-split (ci-chunk x tile-chunk) ----
__global__ void __launch_bounds__(256) rank_kernel(const uint2* __restrict__ cand,
                                                   const unsigned* __restrict__ meta,
                                                   unsigned* __restrict__ partial) {
  int b = blockIdx.z;
  unsigned M = meta[b * META_STRIDE + 1];
  if (M > CAP_) M = CAP_;
  unsigned tb = blockIdx.y * TILE_;
  if (tb >= M) return;
  if ((unsigned)(blockIdx.x * 256) >= M) return;
  __shared__ __align__(16) uint2 tile[TILE_];
  unsigned n = M - tb;
  if (n > TILE_) n = TILE_;
  for (unsigned t = threadIdx.x; t < n; t += 256) tile[t] = cand[(size_t)b * CAP_ + tb + t];
  int ci = blockIdx.x * 256 + threadIdx.x;
  bool act = ci < (int)M;
  uint2 me = make_uint2(0u, 0u);
  if (act) me = cand[(size_t)b * CAP_ + ci];
  unsigned long long my = ((unsigned long long)me.x << 32) | (unsigned long long)(unsigned)(~me.y);
  __syncthreads();
  if (act) {
    unsigned rank = 0;
    unsigned n2 = n >> 1;
    const uint4* t4 = (const uint4*)tile;
    for (unsigned j = 0; j < n2; ++j) {
      uint4 v = t4[j];
      unsigned long long c0 = ((unsigned long long)v.x << 32) | (unsigned long long)(unsigned)(~v.y);
      unsigned long long c1 = ((unsigned long long)v.z << 32) | (unsigned long long)(unsigned)(~v.w);
      rank += (unsigned)(c0 > my) + (unsigned)(c1 > my);
    }
    if (n & 1) {
      uint2 v = tile[n - 1];
      unsigned long long c0 = ((unsigned long long)v.x << 32) | (unsigned long long)(unsigned)(~v.y);
      rank += (unsigned)(c0 > my);
    }
    partial[((size_t)b * NCH_ + blockIdx.y) * CAP_ + ci] = rank;
  }
}

// ---- K5: sum partial ranks, gather anchors/deltas, decode boxes, clip (fused) ----
__global__ void __launch_bounds__(256) scatter_kernel(const uint2* __restrict__ cand,
                                                      const unsigned* __restrict__ meta,
                                                      const unsigned* __restrict__ partial,
                                                      const float4* __restrict__ bbox,
                                                      const float4* __restrict__ anch,
                                                      float4* __restrict__ boxes) {
  int b = blockIdx.y;
  unsigned M = meta[b * META_STRIDE + 1];
  if (M > CAP_) M = CAP_;
  unsigned ci = blockIdx.x * 256 + threadIdx.x;
  if (ci >= M) return;
  unsigned nch = (M + TILE_ - 1) / TILE_;
  const unsigned* pp = partial + (size_t)b * NCH_ * CAP_ + ci;
  unsigned rank = 0;
  for (unsigned c = 0; c < nch; ++c) rank += pp[(size_t)c * CAP_];
  if (rank >= K_) return;
  unsigned idx = cand[(size_t)b * CAP_ + ci].y;
  size_t base = (size_t)b * N_ + idx;
  float4 a = anch[base];
  float4 d = bbox[base];
  float d0 = d.x * 0.1f, d1 = d.y * 0.1f, d2 = d.z * 0.2f, d3 = d.w * 0.2f;
  float h = a.z - a.x, w = a.w - a.y;
  float cy = (a.x + 0.5f * h) + d0 * h;
  float cx = (a.y + 0.5f * w) + d1 * w;
  float h2 = h * expf(d2);
  float w2 = w * expf(d3);
  float y1 = cy - 0.5f * h2, x1 = cx - 0.5f * w2;
  float y2 = cy + 0.5f * h2, x2 = cx + 0.5f * w2;
  y1 = fminf(fmaxf(y1, 0.f), 1.f);
  x1 = fminf(fmaxf(x1, 0.f), 1.f);
  y2 = fminf(fmaxf(y2, 0.f), 1.f);
  x2 = fminf(fmaxf(x2, 0.f), 1.f);
  boxes[(b << 11) + rank] = make_float4(y1, x1, y2, x2);
}

// ---- K6: IoU bitmask — sparse writes (buffer pre-zeroed) + rowAny bitmap ----
__global__ void mask_kernel(const float4* __restrict__ boxes, unsigned long long* __restrict__ mask,
                            unsigned long long* __restrict__ rowAny) {
  int wid = blockIdx.x * 4 + (threadIdx.x >> 6);
  int lane = threadIdx.x & 63;
  int b = wid >> 12;         // 4096 waves per batch
  int rb = (wid >> 5) & 127; // row block of 16
  int jb = wid & 31;         // 64-column block
  if (jb < (rb >> 2)) return;  // strictly-lower word-blocks are all zero
  int j = (jb << 6) + lane;
  float4 bj = boxes[(b << 11) + j];
  float areaJ = (bj.z - bj.x) * (bj.w - bj.y);
#pragma unroll
  for (int r = 0; r < 16; ++r) {
    int i = (rb << 4) + r;
    float4 bi = boxes[(b << 11) + i];
    float areaI = (bi.z - bi.x) * (bi.w - bi.y);
    float yA = fmaxf(bi.x, bj.x), xA = fmaxf(bi.y, bj.y);
    float yB = fminf(bi.z, bj.z), xB = fminf(bi.w, bj.w);
    float ih = fmaxf(yB - yA, 0.f), iw = fmaxf(xB - xA, 0.f);
    float inter = ih * iw;
    float uni = areaI + areaJ - inter;
    float iou = inter / (uni + 1e-8f);
    bool pred = (iou > THR_) && (j > i);
    unsigned long long bits = __ballot(pred);
    if (bits && lane == 0) {
      mask[((size_t)((b << 11) + i) << 5) + jb] = bits;
      atomicOr(&rowAny[b * 32 + (i >> 6)], 1ull << (i & 63));
    }
  }
}

// ---- K7: greedy NMS over sparse "event" rows — 1 wave, no hot-loop barriers ----
// Event rows (rows with any suppression bit) come from rowAny (~100-300 expected).
// Exact: non-event rows never suppress; mask bits are strictly j>i, so processing
// event rows ascending with an alive-check reproduces the greedy scan.
__global__ void __launch_bounds__(64) nms_kernel(const unsigned long long* __restrict__ mask,
                                                 const unsigned long long* __restrict__ rowAny,
                                                 const float4* __restrict__ boxes,
                                                 float4* __restrict__ out) {
  int b = blockIdx.x;
  int lane = threadIdx.x;  // 64 threads = 1 wave
  int w = lane & 31;
  __shared__ unsigned long long rowsBuf[256][32];  // 64 KB event-row staging
  __shared__ unsigned short evRow[2048];
  __shared__ unsigned long long keptw[32];
  __shared__ int pre[32];
  __shared__ short sel[P_];
  for (int r = lane; r < P_; r += 64) sel[r] = -1;
  // 1. event list from rowAny (lanes 0-31 hold the 32 words)
  unsigned long long anyv = (lane < 32) ? rowAny[b * 32 + lane] : 0ull;
  unsigned pc = (unsigned)__popcll(anyv);
  unsigned pref = pc;
#pragma unroll
  for (int off = 1; off < 32; off <<= 1) {
    unsigned tv = __shfl_up(pref, off, 64);
    if ((lane & 31) >= off) pref += tv;
  }
  int E = __shfl((int)pref, 31, 64);
  if (lane < 32) {
    unsigned o = pref - pc;
    unsigned long long bm = anyv;
    while (bm) {
      int i = __ffsll((long long)bm) - 1;
      bm &= bm - 1;
      evRow[o++] = (unsigned short)((lane << 6) + i);
    }
  }
  __syncthreads();
  unsigned long long sup = 0ull;  // lane w owns suppressed word w (mirrored in both halves)
  const unsigned long long* mb = mask + (((size_t)(b << 11)) << 5);
  for (int eb = 0; eb < E; eb += 256) {
    int ne = E - eb;
    if (ne > 256) ne = 256;
    // stage event rows: 2 rows per load instr (half-waves), coalesced 256B/row
    for (int k = (lane >> 5); k < ne; k += 2) {
      int r = evRow[eb + k];
      rowsBuf[k][w] = mb[((size_t)r << 5) + w];
    }
    __syncthreads();
    // serial event loop, 2-deep LDS prefetch
    int i0 = evRow[eb];
    unsigned long long v0 = rowsBuf[0][w];
    int i1 = 0;
    unsigned long long v1 = 0ull;
    if (ne > 1) { i1 = evRow[eb + 1]; v1 = rowsBuf[1][w]; }
    for (int e = 0; e < ne; ++e) {
      int i2 = 0;
      unsigned long long v2 = 0ull;
      if (e + 2 < ne) { i2 = evRow[eb + e + 2]; v2 = rowsBuf[e + 2][w]; }
      int wi = i0 >> 6;
      unsigned long long sw = readlane64(sup, wi);
      if (!((sw >> (i0 & 63)) & 1ull)) sup |= v0;
      i0 = i1; v0 = v1; i1 = i2; v1 = v2;
    }
    __syncthreads();
  }
  if (lane < 32) keptw[lane] = ~sup;
  __syncthreads();
  if (lane == 0) {
    int run = 0;
    for (int c = 0; c < 32; ++c) { pre[c] = run; run += (int)__popcll(keptw[c]); }
  }
  __syncthreads();
  for (int i = lane; i < K_; i += 64) {
    int c = i >> 6, k2 = i & 63;
    unsigned long long km = keptw[c];
    if ((km >> k2) & 1ull) {
      int rank = pre[c] + (int)__popcll(km & ((1ull << k2) - 1ull));
      if (rank < P_) sel[rank] = (short)i;
    }
  }
  __syncthreads();
  for (int r = lane; r < P_; r += 64) {
    int i = sel[r];
    float4 v = make_float4(0.f, 0.f, 0.f, 0.f);
    if (i >= 0) v = boxes[(b << 11) + i];
    out[b * P_ + r] = v;
  }
}

extern "C" void kernel_launch(void* const* d_in, const int* in_sizes, int n_in,
                              void* d_out, int out_size, void* d_ws, size_t ws_size,
                              hipStream_t stream) {
  const float4* probs4 = (const float4*)d_in[0];     // (B,N,2) viewed as float4
  const float4* bbox   = (const float4*)d_in[1];     // (B,N,4)
  const float4* anch   = (const float4*)d_in[2];     // (B,N,4)
  char* ws = (char*)d_ws;
  unsigned* hist = (unsigned*)(ws + OFF_HIST);
  unsigned* meta = (unsigned*)(ws + OFF_META);
  unsigned long long* rowAny = (unsigned long long*)(ws + OFF_ROWANY);
  uint2* cand = (uint2*)(ws + OFF_CAND);
  float4* boxes = (float4*)(ws + OFF_BOX);
  unsigned long long* mask = (unsigned long long*)(ws + OFF_MASK);
  unsigned* partial = (unsigned*)(ws + OFF_PART);
  float4* out = (float4*)d_out;

  hipMemsetAsync(ws, 0, OFF_CAND, stream);  // zero hist + meta + rowAny

  hist_kernel<<<dim3(124, B_), 512, 0, stream>>>(probs4, hist, (uint4*)mask);  // 124*4096 >= 500k f4
  select_kernel<<<B_, 256, 0, stream>>>(hist, meta);
  compact_kernel<<<dim3(245, B_), 256, 0, stream>>>(probs4, meta, cand);       // 245*2048 >= 500k f4
  rank_kernel<<<dim3(CAP_ / 256, NCH_, B_), 256, 0, stream>>>(cand, meta, partial);
  scatter_kernel<<<dim3(CAP_ / 256, B_), 256, 0, stream>>>(cand, meta, partial, bbox, anch, boxes);
  mask_kernel<<<(B_ * 128 * 32) / 4, 256, 0, stream>>>(boxes, mask, rowAny);
  nms_kernel<<<B_, 64, 0, stream>>>(mask, rowAny, boxes, out);
}

// Round 4
// 250.768 us; speedup vs baseline: 1.2222x; 1.2222x over previous
//
#include <hip/hip_runtime.h>

#define B_ 4
#define N_ 1000000
#define K_ 2048
#define P_ 1000
#define CAP_ 8192
#define THR_ 0.7f
#define NF4_ 500000     // float4 count per batch of (N,2) float array
#define META_STRIDE 32  // u32 per batch -> 128 B: counters on separate cache lines
#define TILE_ 512       // rank tile (candidates per tile-chunk)
#define NCH_ (CAP_ / TILE_)  // 16 tile chunks max
#define NSTAGE 448      // nms: event rows staged in LDS (112 KB)
#define CROW 1536       // nms phase-1 row cutoff (24 x 64)

// ---- workspace layout (bytes) ----
// hist   : B * 65536 * 4 = 1,048,576
// meta   : 1024
// coarse : B * 256 * 4 = 4,096
// rowAny : B * 32 * 8 = 1,024      (2048-bit "row has suppression bits" bitmap)
// cand   : B * CAP * 8 = 262,144
// boxes  : B * K * 16 = 131,072
// mask   : B * K * 32 * 8 = 2,097,152  (dense writes; lower-tri words never read)
//   partial-rank array (B * NCH * CAP * 4 = 2,097,152) ALIASES mask:
//   rank writes it, scatter consumes it, THEN mask_kernel overwrites.
#define OFF_HIST 0
#define OFF_META 1048576
#define OFF_COARSE 1049600
#define OFF_ROWANY 1053696
#define OFF_CAND 1054720
#define OFF_BOX  1316864
#define OFF_MASK 1447936

__device__ __forceinline__ unsigned fkey(float f) {
  unsigned u = __float_as_uint(f);
  return (u & 0x80000000u) ? ~u : (u | 0x80000000u);
}

__device__ __forceinline__ unsigned long long readlane64(unsigned long long v, int l) {
  unsigned lo = (unsigned)__builtin_amdgcn_readlane((int)(unsigned)(v & 0xffffffffull), l);
  unsigned hi = (unsigned)__builtin_amdgcn_readlane((int)(unsigned)(v >> 32), l);
  return ((unsigned long long)hi << 32) | (unsigned long long)lo;
}

#define PIN16(k) asm volatile("" : "+v"(k[0]), "+v"(k[1]), "+v"(k[2]), "+v"(k[3]), \
                                   "+v"(k[4]), "+v"(k[5]), "+v"(k[6]), "+v"(k[7]), \
                                   "+v"(k[8]), "+v"(k[9]), "+v"(k[10]), "+v"(k[11]), \
                                   "+v"(k[12]), "+v"(k[13]), "+v"(k[14]), "+v"(k[15]))

// ---- K1: LDS-privatized histogram of top-16 bits of monotonic key ----
__global__ void __launch_bounds__(1024) hist_kernel(const float4* __restrict__ probs4,
                                                    unsigned* __restrict__ hist) {
  int b = blockIdx.y;
  __shared__ unsigned h[32768];
  for (int i = threadIdx.x; i < 32768; i += 1024) h[i] = 0u;
  __syncthreads();
  const float4* p4 = probs4 + (size_t)b * NF4_;
  int base = blockIdx.x * 8192;
  float4 v[8];
#pragma unroll
  for (int c = 0; c < 8; ++c) {
    int i4 = base + c * 1024 + threadIdx.x;
    v[c] = (i4 < NF4_) ? p4[i4] : make_float4(0.f, 0.f, 0.f, 0.f);
  }
  unsigned k[16];
#pragma unroll
  for (int c = 0; c < 8; ++c) { k[2 * c] = fkey(v[c].y) >> 16; k[2 * c + 1] = fkey(v[c].w) >> 16; }
  PIN16(k);
#pragma unroll
  for (int c = 0; c < 8; ++c) {
    int i4 = base + c * 1024 + threadIdx.x;
    if (i4 < NF4_) {
      unsigned b0 = k[2 * c], b1 = k[2 * c + 1];
      atomicAdd(&h[b0 >> 1], 1u << ((b0 & 1u) << 4));
      atomicAdd(&h[b1 >> 1], 1u << ((b1 & 1u) << 4));
    }
  }
  __syncthreads();
  unsigned* g = hist + ((size_t)b << 16);
  for (int w = threadIdx.x; w < 32768; w += 1024) {
    unsigned x = h[w];
    if (x) {
      unsigned c0 = x & 0xFFFFu, c1 = x >> 16;
      if (c0) atomicAdd(&g[2 * w], c0);
      if (c1) atomicAdd(&g[2 * w + 1], c1);
    }
  }
}

// ---- K2a: coarse sums — one wave per 256-bucket group ----
__global__ void __launch_bounds__(64) coarse_kernel(const unsigned* __restrict__ hist,
                                                    unsigned* __restrict__ coarse) {
  int b = blockIdx.y, g = blockIdx.x, lane = threadIdx.x;
  const uint4* h4 = (const uint4*)(hist + (((size_t)b) << 16) + ((size_t)g << 8));
  uint4 v = h4[lane];
  unsigned s = v.x + v.y + v.z + v.w;
#pragma unroll
  for (int off = 32; off >= 1; off >>= 1) s += __shfl_xor(s, off, 64);
  if (lane == 0) coarse[b * 256 + g] = s;
}

// ---- K2b: find smallest bucket cb with count(bucket >= cb) >= K ----
__global__ void select_kernel(const unsigned* __restrict__ hist, const unsigned* __restrict__ coarse,
                              unsigned* __restrict__ meta) {
  int b = blockIdx.x, t = threadIdx.x;  // 256 threads
  __shared__ unsigned suf[256];
  __shared__ int tc_s;
  __shared__ unsigned above_s;
  const unsigned* g = hist + ((size_t)b << 16);
  suf[t] = coarse[b * 256 + t];
  __syncthreads();
  for (int off = 1; off < 256; off <<= 1) {
    unsigned add = (t + off < 256) ? suf[t + off] : 0u;
    __syncthreads();
    suf[t] += add;
    __syncthreads();
  }
  unsigned nxt = (t < 255) ? suf[t + 1] : 0u;
  if (suf[t] >= K_ && (t == 255 || nxt < K_)) { tc_s = t; above_s = nxt; }
  __syncthreads();
  int tc = tc_s;
  unsigned above = above_s;
  unsigned bs = g[tc * 256 + t];
  __syncthreads();
  suf[t] = bs;
  __syncthreads();
  for (int off = 1; off < 256; off <<= 1) {
    unsigned add = (t + off < 256) ? suf[t + off] : 0u;
    __syncthreads();
    suf[t] += add;
    __syncthreads();
  }
  unsigned nxt2 = (t < 255) ? suf[t + 1] : 0u;
  if (above + suf[t] >= K_ && (t == 255 || above + nxt2 < K_))
    meta[b * META_STRIDE + 0] = (unsigned)(tc * 256 + t);
}

// ---- K3: compact candidates (bucket >= cb), LDS-buffered, 1 global atomic/block ----
__global__ void __launch_bounds__(256) compact_kernel(const float4* __restrict__ probs4,
                                                      unsigned* __restrict__ meta,
                                                      uint2* __restrict__ cand) {
  int b = blockIdx.y;
  __shared__ unsigned lcnt, gbase_s;
  __shared__ uint2 buf[4096];
  if (threadIdx.x == 0) lcnt = 0u;
  __syncthreads();
  unsigned cb = meta[b * META_STRIDE + 0];
  const float4* p4 = probs4 + (size_t)b * NF4_;
  int base = blockIdx.x * 2048;
  int lane = threadIdx.x & 63;
  float4 v[8];
#pragma unroll
  for (int c = 0; c < 8; ++c) {
    int i4 = base + c * 256 + threadIdx.x;
    v[c] = (i4 < NF4_) ? p4[i4] : make_float4(0.f, 0.f, 0.f, 0.f);
  }
  unsigned k[16];
#pragma unroll
  for (int c = 0; c < 8; ++c) { k[2 * c] = fkey(v[c].y); k[2 * c + 1] = fkey(v[c].w); }
  PIN16(k);
#pragma unroll
  for (int c = 0; c < 8; ++c) {
#pragma unroll
    for (int s = 0; s < 2; ++s) {
      int i4 = base + c * 256 + threadIdx.x;
      unsigned key = k[2 * c + s];
      bool pass = (i4 < NF4_) && ((key >> 16) >= cb);
      unsigned long long m = __ballot(pass);
      if (m) {
        int leader = __ffsll(m) - 1;
        unsigned wbase = 0;
        if (lane == leader) wbase = atomicAdd(&lcnt, (unsigned)__popcll(m));
        wbase = __shfl(wbase, leader, 64);
        if (pass) {
          unsigned pos = wbase + (unsigned)__popcll(m & ((1ull << lane) - 1ull));
          buf[pos] = make_uint2(key, (unsigned)(2 * i4 + s));
        }
      }
    }
  }
  __syncthreads();
  unsigned cnt = lcnt;
  if (threadIdx.x == 0) gbase_s = atomicAdd(&meta[b * META_STRIDE + 1], cnt);
  __syncthreads();
  unsigned gbase = gbase_s;
  for (unsigned i = threadIdx.x; i < cnt; i += 256) {
    unsigned pos = gbase + i;
    if (pos < CAP_) cand[(size_t)b * CAP_ + pos] = buf[i];
  }
}

// ---- K4: exact rank by counting, 2D-split (ci-chunk x tile-chunk) ----
__global__ void __launch_bounds__(256) rank_kernel(const uint2* __restrict__ cand,
                                                   const unsigned* __restrict__ meta,
                                                   unsigned* __restrict__ partial) {
  int b = blockIdx.z;
  unsigned M = meta[b * META_STRIDE + 1];
  if (M > CAP_) M = CAP_;
  unsigned tb = blockIdx.y * TILE_;
  if (tb >= M) return;
  if ((unsigned)(blockIdx.x * 256) >= M) return;
  __shared__ __align__(16) uint2 tile[TILE_];
  unsigned n = M - tb;
  if (n > TILE_) n = TILE_;
  for (unsigned t = threadIdx.x; t < n; t += 256) tile[t] = cand[(size_t)b * CAP_ + tb + t];
  int ci = blockIdx.x * 256 + threadIdx.x;
  bool act = ci < (int)M;
  uint2 me = make_uint2(0u, 0u);
  if (act) me = cand[(size_t)b * CAP_ + ci];
  unsigned long long my = ((unsigned long long)me.x << 32) | (unsigned long long)(unsigned)(~me.y);
  __syncthreads();
  if (act) {
    unsigned rank = 0;
    unsigned n2 = n >> 1;
    const uint4* t4 = (const uint4*)tile;
    for (unsigned j = 0; j < n2; ++j) {
      uint4 v = t4[j];
      unsigned long long c0 = ((unsigned long long)v.x << 32) | (unsigned long long)(unsigned)(~v.y);
      unsigned long long c1 = ((unsigned long long)v.z << 32) | (unsigned long long)(unsigned)(~v.w);
      rank += (unsigned)(c0 > my) + (unsigned)(c1 > my);
    }
    if (n & 1) {
      uint2 v = tile[n - 1];
      unsigned long long c0 = ((unsigned long long)v.x << 32) | (unsigned long long)(unsigned)(~v.y);
      rank += (unsigned)(c0 > my);
    }
    partial[((size_t)b * NCH_ + blockIdx.y) * CAP_ + ci] = rank;
  }
}

// ---- K5: sum partial ranks, gather anchors/deltas, decode boxes, clip (fused) ----
__global__ void __launch_bounds__(256) scatter_kernel(const uint2* __restrict__ cand,
                                                      const unsigned* __restrict__ meta,
                                                      const unsigned* __restrict__ partial,
                                                      const float4* __restrict__ bbox,
                                                      const float4* __restrict__ anch,
                                                      float4* __restrict__ boxes) {
  int b = blockIdx.y;
  unsigned M = meta[b * META_STRIDE + 1];
  if (M > CAP_) M = CAP_;
  unsigned ci = blockIdx.x * 256 + threadIdx.x;
  if (ci >= M) return;
  unsigned nch = (M + TILE_ - 1) / TILE_;
  const unsigned* pp = partial + (size_t)b * NCH_ * CAP_ + ci;
  unsigned rank = 0;
  for (unsigned c = 0; c < nch; ++c) rank += pp[(size_t)c * CAP_];
  if (rank >= K_) return;
  unsigned idx = cand[(size_t)b * CAP_ + ci].y;
  size_t base = (size_t)b * N_ + idx;
  float4 a = anch[base];
  float4 d = bbox[base];
  float d0 = d.x * 0.1f, d1 = d.y * 0.1f, d2 = d.z * 0.2f, d3 = d.w * 0.2f;
  float h = a.z - a.x, w = a.w - a.y;
  float cy = (a.x + 0.5f * h) + d0 * h;
  float cx = (a.y + 0.5f * w) + d1 * w;
  float h2 = h * expf(d2);
  float w2 = w * expf(d3);
  float y1 = cy - 0.5f * h2, x1 = cx - 0.5f * w2;
  float y2 = cy + 0.5f * h2, x2 = cx + 0.5f * w2;
  y1 = fminf(fmaxf(y1, 0.f), 1.f);
  x1 = fminf(fmaxf(x1, 0.f), 1.f);
  y2 = fminf(fmaxf(y2, 0.f), 1.f);
  x2 = fminf(fmaxf(x2, 0.f), 1.f);
  boxes[(b << 11) + rank] = make_float4(y1, x1, y2, x2);
}

// ---- K6: IoU suppression bitmask (dense upper-tri writes) + rowAny bitmap ----
__global__ void mask_kernel(const float4* __restrict__ boxes, unsigned long long* __restrict__ mask,
                            unsigned long long* __restrict__ rowAny) {
  int wid = blockIdx.x * 4 + (threadIdx.x >> 6);
  int lane = threadIdx.x & 63;
  int b = wid >> 12;         // 4096 waves per batch
  int rb = (wid >> 5) & 127; // row block of 16
  int jb = wid & 31;         // 64-column block
  if (jb < (rb >> 2)) return;  // strictly-lower word-blocks are never read
  int j = (jb << 6) + lane;
  float4 bj = boxes[(b << 11) + j];
  float areaJ = (bj.z - bj.x) * (bj.w - bj.y);
#pragma unroll
  for (int r = 0; r < 16; ++r) {
    int i = (rb << 4) + r;
    float4 bi = boxes[(b << 11) + i];
    float areaI = (bi.z - bi.x) * (bi.w - bi.y);
    float yA = fmaxf(bi.x, bj.x), xA = fmaxf(bi.y, bj.y);
    float yB = fminf(bi.z, bj.z), xB = fminf(bi.w, bj.w);
    float ih = fmaxf(yB - yA, 0.f), iw = fmaxf(xB - xA, 0.f);
    float inter = ih * iw;
    float uni = areaI + areaJ - inter;
    float iou = inter / (uni + 1e-8f);
    bool pred = (iou > THR_) && (j > i);
    unsigned long long bits = __ballot(pred);
    if (lane == 0) {
      mask[((size_t)((b << 11) + i) << 5) + jb] = bits;
      if (bits) atomicOr(&rowAny[b * 32 + (i >> 6)], 1ull << (i & 63));
    }
  }
}

// ---- K7: greedy NMS via Jacobi fixpoint over sparse event rows ----
// kept[i] = !exists j<i: kept[j] & m[j][i] is an ACYCLIC boolean system (mask is
// strictly upper-triangular). Jacobi: sup' = OR of mask rows of alive event rows;
// converges from any start in <= chain-depth+1 iterations (bit i frozen-correct
// after depth(i) iters); sup'==sup certifies the unique fixpoint. Fully parallel.
// Phase 1 restricts to rows < CROW; if kept count there >= P_, rows >= CROW can't
// reach the output (their rank >= P_). Phase 2 (rare) extends to all events.
__global__ void __launch_bounds__(256) nms_kernel(const unsigned long long* __restrict__ mask,
                                                  const unsigned long long* __restrict__ rowAny,
                                                  const float4* __restrict__ boxes,
                                                  float4* __restrict__ out) {
  int b = blockIdx.x;
  int t = threadIdx.x;
  int w = t & 31, g = t >> 5;
  __shared__ unsigned long long rowsBuf[NSTAGE][32];  // 112 KB event-row staging
  __shared__ unsigned short evRow[2048];
  __shared__ unsigned long long supA[32], supB[32];
  __shared__ int pre[32];
  __shared__ short sel[P_];
  __shared__ int E_s, EC_s, chg_s, cnt_s;
  for (int r = t; r < P_; r += 256) sel[r] = -1;
  if (t < 32) { supA[t] = 0ull; supB[t] = 0ull; }
  if (t == 0) { E_s = 0; EC_s = 0; chg_s = 0; }
  // ---- event list from rowAny (wave 0) ----
  if (t < 64) {
    unsigned long long anyv = (t < 32) ? rowAny[b * 32 + t] : 0ull;
    unsigned pc = (unsigned)__popcll(anyv);
    unsigned pref = pc;
#pragma unroll
    for (int off = 1; off < 32; off <<= 1) {
      unsigned tv = __shfl_up(pref, off, 64);
      if ((t & 31) >= off) pref += tv;
    }
    if (t == 31) E_s = (int)pref;
    if (t == 23) EC_s = (int)pref;  // events with row < CROW (CROW = 24*64)
    if (t < 32) {
      unsigned o = pref - pc;
      unsigned long long bm = anyv;
      while (bm) {
        int i = __ffsll((long long)bm) - 1;
        bm &= bm - 1;
        evRow[o++] = (unsigned short)((t << 6) + i);
      }
    }
  }
  __syncthreads();
  int E = E_s, EC = EC_s;
  const unsigned long long* mb = mask + (((size_t)(b << 11)) << 5);
  // ---- batched staging: 8 loads in flight per thread, then LDS commit ----
  int ns = (E < NSTAGE) ? E : NSTAGE;
  for (int base = 0; base < ns; base += 64) {
    unsigned long long v[8];
#pragma unroll
    for (int j = 0; j < 8; ++j) {
      int e = base + j * 8 + g;
      v[j] = 0ull;
      if (e < ns) {
        int r = (int)evRow[e];
        if (w >= (r >> 6)) v[j] = mb[((size_t)r << 5) + w];  // lower-tri words: garbage, never read
      }
    }
#pragma unroll
    for (int j = 0; j < 8; ++j) {
      int e = base + j * 8 + g;
      if (e < ns) rowsBuf[e][w] = v[j];
    }
  }
  __syncthreads();
  // ---- Jacobi fixpoint ----
  unsigned long long* cur = supA;
  unsigned long long* nxt = supB;
  int limit = EC;
  for (;;) {
    unsigned long long acc = 0ull;
    for (int e = g; e < limit; e += 8) {
      int r = (int)evRow[e];
      int rw = r >> 6;
      if (w >= rw) {
        unsigned long long sw = cur[rw];
        if (!((sw >> (r & 63)) & 1ull))
          acc |= (e < NSTAGE) ? rowsBuf[e][w] : mb[((size_t)r << 5) + w];
      }
    }
    if (acc) atomicOr((unsigned long long*)&nxt[w], acc);
    __syncthreads();
    if (t < 32) {
      if (t == 0) chg_s = 0;                 // wave-lockstep: ordered before compares below
      if (nxt[t] != cur[t]) chg_s = 1;
      cur[t] = 0ull;                         // becomes the fresh nxt after swap
    }
    __syncthreads();
    { unsigned long long* tmp = cur; cur = nxt; nxt = tmp; }
    if (chg_s) continue;
    if (limit >= E) break;                   // converged on full system
    if (t == 0) {
      int c = 0;
      for (int i = 0; i < 24; ++i) c += (int)__popcll(cur[i]);
      cnt_s = CROW - c;                      // exact kept count among rows < CROW
    }
    __syncthreads();
    if (cnt_s >= P_) break;                  // output confined to rows < CROW
    limit = E;                               // rare fallback: extend to all events
  }
  // ---- selection: first P_ kept rows ----
  if (t == 0) {
    int run = 0;
    for (int c = 0; c < 32; ++c) { pre[c] = run; run += (int)__popcll(~cur[c]); }
  }
  __syncthreads();
  for (int i = t; i < K_; i += 256) {
    int c = i >> 6, k2 = i & 63;
    unsigned long long km = ~cur[c];
    if ((km >> k2) & 1ull) {
      int rank = pre[c] + (int)__popcll(km & ((1ull << k2) - 1ull));
      if (rank < P_) sel[rank] = (short)i;
    }
  }
  __syncthreads();
  for (int r = t; r < P_; r += 256) {
    int i = sel[r];
    float4 v = make_float4(0.f, 0.f, 0.f, 0.f);
    if (i >= 0) v = boxes[(b << 11) + i];
    out[b * P_ + r] = v;
  }
}

extern "C" void kernel_launch(void* const* d_in, const int* in_sizes, int n_in,
                              void* d_out, int out_size, void* d_ws, size_t ws_size,
                              hipStream_t stream) {
  const float4* probs4 = (const float4*)d_in[0];     // (B,N,2) viewed as float4
  const float4* bbox   = (const float4*)d_in[1];     // (B,N,4)
  const float4* anch   = (const float4*)d_in[2];     // (B,N,4)
  char* ws = (char*)d_ws;
  unsigned* hist = (unsigned*)(ws + OFF_HIST);
  unsigned* meta = (unsigned*)(ws + OFF_META);
  unsigned* coarse = (unsigned*)(ws + OFF_COARSE);
  unsigned long long* rowAny = (unsigned long long*)(ws + OFF_ROWANY);
  uint2* cand = (uint2*)(ws + OFF_CAND);
  float4* boxes = (float4*)(ws + OFF_BOX);
  unsigned long long* mask = (unsigned long long*)(ws + OFF_MASK);
  unsigned* partial = (unsigned*)(ws + OFF_MASK);  // aliases mask (consumed before mask written)
  float4* out = (float4*)d_out;

  hipMemsetAsync(ws, 0, OFF_CAND, stream);  // zero hist + meta + coarse + rowAny

  hist_kernel<<<dim3(62, B_), 1024, 0, stream>>>(probs4, hist);           // 62*8192 >= 500k f4
  coarse_kernel<<<dim3(256, B_), 64, 0, stream>>>(hist, coarse);
  select_kernel<<<B_, 256, 0, stream>>>(hist, coarse, meta);
  compact_kernel<<<dim3(245, B_), 256, 0, stream>>>(probs4, meta, cand);  // 245*2048 >= 500k f4
  rank_kernel<<<dim3(CAP_ / 256, NCH_, B_), 256, 0, stream>>>(cand, meta, partial);
  scatter_kernel<<<dim3(CAP_ / 256, B_), 256, 0, stream>>>(cand, meta, partial, bbox, anch, boxes);
  mask_kernel<<<(B_ * 128 * 32) / 4, 256, 0, stream>>>(boxes, mask, rowAny);
  nms_kernel<<<B_, 256, 0, stream>>>(mask, rowAny, boxes, out);
}